// Round 1
// baseline (347.498 us; speedup 1.0000x reference)
//
#include <hip/hip_runtime.h>
#include <hip/hip_cooperative_groups.h>
#include <math.h>

namespace cg = cooperative_groups;

// Problem constants (match reference)
constexpr int NB   = 8;            // batch
constexpr int ND   = 8;            // embedding dim
constexpr int NH   = 512;
constexpr int NW   = 1024;
constexpr int NP   = NH * NW;      // pixels per image = 524288
constexpr int NG   = NP / 4;       // float4 groups per image = 131072
constexpr int BPB  = 64;           // blocks per batch image
constexpr int NBLK = NB * BPB;     // 512 blocks total = exactly 2 per CU
constexpr int GPB  = NG / BPB;     // float4 groups per block = 2048
constexpr int NK   = 5;            // instance labels 1..NK
constexpr int NVAL = NK * ND + NK; // 45 reduced values in phase 1

constexpr float DELTA_V     = 0.5f;
constexpr float TWO_DELTA_D = 6.0f;   // 2 * DELTA_D
constexpr float GAMMA       = 0.001f;

__device__ __forceinline__ float wave_sum(float v) {
#pragma unroll
    for (int off = 32; off > 0; off >>= 1) v += __shfl_down(v, off, 64);
    return v;
}

// Single fused cooperative kernel:
//   phase 1: per-block partial sums/counts (plain stores, no atomics, no init)
//   grid.sync()
//   centers : every block reduces its image's 64 partials (L2-hot), -> registers
//   phase 2: variance hinge sums (embedding re-read is L3-resident)
//   grid.sync()
//   phase 3: block 0 epilogue, 8-way parallel over batch
__global__ __launch_bounds__(256, 2) void fused_kernel(
        const float* __restrict__ emb,
        const int*   __restrict__ mask,
        float* __restrict__ part1,   // [NBLK][NVAL]
        float* __restrict__ gcent,   // [NB][NK][ND] centers
        float* __restrict__ gcnt,    // [NB][NK]
        float* __restrict__ part2,   // [NBLK][NK]
        float* __restrict__ out) {
    const cg::grid_group grid = cg::this_grid();
    const int b   = blockIdx.x / BPB;
    const int blk = blockIdx.x % BPB;
    const long base = (long)blk * GPB;
    const int lane = threadIdx.x & 63;
    const int wave = threadIdx.x >> 6;

    const float4* emb4 = (const float4*)emb;
    const int4*   m4p  = (const int4*)mask + (long)b * NG;

    __shared__ float part[4][NVAL];
    __shared__ float red[NVAL];
    __shared__ float csh[NK][ND];
    __shared__ float vsh[NB][NK];
    __shared__ float bl[4][NB];      // lv, ld, lr, has per image

    // ================= phase 1: per-(b,k) embedding sums + counts =================
    float acc[NK][ND];
    float cnt[NK];
#pragma unroll
    for (int k = 0; k < NK; ++k) {
        cnt[k] = 0.f;
#pragma unroll
        for (int d = 0; d < ND; ++d) acc[k][d] = 0.f;
    }

    for (int it = threadIdx.x; it < GPB; it += 256) {
        const long g = base + it;
        const int4 m = m4p[g];
        float4 e[ND];
#pragma unroll
        for (int d = 0; d < ND; ++d)
            e[d] = emb4[((long)(b * ND + d)) * NG + g];
        const int labs[4] = {m.x, m.y, m.z, m.w};
#pragma unroll
        for (int j = 0; j < 4; ++j) {
            const int lab = labs[j];
#pragma unroll
            for (int k = 0; k < NK; ++k) {
                const float is = (lab == k + 1) ? 1.f : 0.f;
                cnt[k] += is;
#pragma unroll
                for (int d = 0; d < ND; ++d)
                    acc[k][d] = fmaf(is, ((const float*)&e[d])[j], acc[k][d]);
            }
        }
    }

    // block reduction -> per-block partials (plain stores, dedicated slots)
#pragma unroll
    for (int k = 0; k < NK; ++k) {
#pragma unroll
        for (int d = 0; d < ND; ++d) {
            const float r = wave_sum(acc[k][d]);
            if (lane == 0) part[wave][k * ND + d] = r;
        }
        const float rc = wave_sum(cnt[k]);
        if (lane == 0) part[wave][NK * ND + k] = rc;
    }
    __syncthreads();
    if (threadIdx.x < NVAL) {
        part1[blockIdx.x * NVAL + threadIdx.x] =
            part[0][threadIdx.x] + part[1][threadIdx.x] +
            part[2][threadIdx.x] + part[3][threadIdx.x];
    }

    grid.sync();

    // ============== centers: every block reduces its own image's partials ==============
    if (threadIdx.x < NVAL) {
        const float* p = part1 + (long)b * BPB * NVAL + threadIdx.x;
        float s = 0.f;
#pragma unroll 8
        for (int i = 0; i < BPB; ++i) s += p[(long)i * NVAL];
        red[threadIdx.x] = s;
    }
    __syncthreads();
    if (threadIdx.x < NK * ND) {
        const int k = threadIdx.x / ND;
        const float c = red[threadIdx.x] / fmaxf(red[NK * ND + k], 1.f);
        csh[k][threadIdx.x % ND] = c;
        if (blk == 0) gcent[b * NK * ND + threadIdx.x] = c;   // for epilogue
    } else if (threadIdx.x < NVAL) {
        if (blk == 0) gcnt[b * NK + (threadIdx.x - NK * ND)] = red[threadIdx.x];
    }
    __syncthreads();

    float c[NK][ND];
#pragma unroll
    for (int k = 0; k < NK; ++k)
#pragma unroll
        for (int d = 0; d < ND; ++d) c[k][d] = csh[k][d];

    // ================= phase 2: per-(b,k) variance hinge sums =================
    float vacc[NK] = {0.f, 0.f, 0.f, 0.f, 0.f};
    for (int it = threadIdx.x; it < GPB; it += 256) {
        const long g = base + it;
        const int4 m = m4p[g];
        float4 e[ND];
#pragma unroll
        for (int d = 0; d < ND; ++d)
            e[d] = emb4[((long)(b * ND + d)) * NG + g];
        const int labs[4] = {m.x, m.y, m.z, m.w};
#pragma unroll
        for (int j = 0; j < 4; ++j) {
            const int lab = labs[j];
            float dsq = 0.f;
#pragma unroll
            for (int d = 0; d < ND; ++d) {
                float cd = c[0][d];
                cd = (lab == 2) ? c[1][d] : cd;
                cd = (lab == 3) ? c[2][d] : cd;
                cd = (lab == 4) ? c[3][d] : cd;
                cd = (lab == 5) ? c[4][d] : cd;
                const float diff = ((const float*)&e[d])[j] - cd;
                dsq = fmaf(diff, diff, dsq);
            }
            const float dist = sqrtf(dsq);
            float hv = fmaxf(dist - DELTA_V, 0.f);
            const float val = hv * hv;
#pragma unroll
            for (int k = 0; k < NK; ++k)
                vacc[k] += (lab == k + 1) ? val : 0.f;
        }
    }

#pragma unroll
    for (int k = 0; k < NK; ++k) {
        const float r = wave_sum(vacc[k]);
        if (lane == 0) part[wave][k] = r;
    }
    __syncthreads();
    if (threadIdx.x < NK) {
        part2[blockIdx.x * NK + threadIdx.x] =
            part[0][threadIdx.x] + part[1][threadIdx.x] +
            part[2][threadIdx.x] + part[3][threadIdx.x];
    }

    grid.sync();

    // ================= phase 3: epilogue (block 0 only) =================
    if (blockIdx.x != 0) return;

    if (threadIdx.x < NB * NK) {
        const int bb = threadIdx.x / NK, k = threadIdx.x % NK;
        const float* p = part2 + (long)bb * BPB * NK + k;
        float s = 0.f;
#pragma unroll 8
        for (int i = 0; i < BPB; ++i) s += p[(long)i * NK];
        vsh[bb][k] = s;
    }
    __syncthreads();

    if (threadIdx.x < NB) {
        const int bb = threadIdx.x;
        float cw[NK][ND];
        float cc[NK];
        bool  pres[NK];
        float N = 0.f;
#pragma unroll
        for (int k = 0; k < NK; ++k) {
            cc[k]   = gcnt[bb * NK + k];
            pres[k] = cc[k] > 0.f;
            if (pres[k]) N += 1.f;
#pragma unroll
            for (int d = 0; d < ND; ++d)
                cw[k][d] = gcent[bb * NK * ND + k * ND + d];
        }
        // variance loss
        float lv = 0.f;
#pragma unroll
        for (int k = 0; k < NK; ++k)
            if (pres[k]) lv += vsh[bb][k] / fmaxf(cc[k], 1.f);
        lv /= fmaxf(N, 1.f);
        // distance loss (pairwise i<j)
        float ld = 0.f;
#pragma unroll
        for (int i = 0; i < NK; ++i)
#pragma unroll
            for (int j = i + 1; j < NK; ++j)
                if (pres[i] && pres[j]) {
                    float dsq = 0.f;
#pragma unroll
                    for (int d = 0; d < ND; ++d) {
                        const float df = cw[i][d] - cw[j][d];
                        dsq = fmaf(df, df, dsq);
                    }
                    const float t = fmaxf(TWO_DELTA_D - sqrtf(dsq), 0.f);
                    ld += t * t;
                }
        const float npairs = N * (N - 1.f) * 0.5f;
        ld /= (N > 1.f) ? npairs : 1.f;
        // regularization
        float lr = 0.f;
#pragma unroll
        for (int k = 0; k < NK; ++k)
            if (pres[k]) {
                float sq = 0.f;
#pragma unroll
                for (int d = 0; d < ND; ++d) sq = fmaf(cw[k][d], cw[k][d], sq);
                lr += sqrtf(sq);
            }
        lr /= fmaxf(N, 1.f);

        const float has = (N > 0.f) ? 1.f : 0.f;
        bl[0][bb] = lv * has;
        bl[1][bb] = ld * has;
        bl[2][bb] = lr * has;
        bl[3][bb] = has;
    }
    __syncthreads();
    if (threadIdx.x == 0) {
        float tv = 0.f, td = 0.f, tr = 0.f, hs = 0.f;
        for (int bb = 0; bb < NB; ++bb) {
            tv += bl[0][bb]; td += bl[1][bb]; tr += bl[2][bb]; hs += bl[3][bb];
        }
        const float denom = fmaxf(hs, 1.f);
        tv /= denom; td /= denom; tr /= denom;
        out[0] = tv + td + GAMMA * tr;
        out[1] = tv;
        out[2] = td;
        out[3] = tr;
    }
}

extern "C" void kernel_launch(void* const* d_in, const int* in_sizes, int n_in,
                              void* d_out, int out_size, void* d_ws, size_t ws_size,
                              hipStream_t stream) {
    const float* emb  = (const float*)d_in[0];
    const int*   mask = (const int*)d_in[1];
    float* out = (float*)d_out;

    // Workspace layout (all fully overwritten each run; no init needed)
    float* part1 = (float*)d_ws;                     // NBLK*NVAL = 23040 floats
    float* gcent = part1 + NBLK * NVAL;              // NB*NK*ND  = 320
    float* gcnt  = gcent + NB * NK * ND;             // NB*NK     = 40
    float* part2 = gcnt  + NB * NK;                  // NBLK*NK   = 2560

    void* args[] = { (void*)&emb, (void*)&mask, (void*)&part1, (void*)&gcent,
                     (void*)&gcnt, (void*)&part2, (void*)&out };
    hipLaunchCooperativeKernel((const void*)fused_kernel, dim3(NBLK), dim3(256),
                               args, 0, stream);
}

// Round 2
// 257.374 us; speedup vs baseline: 1.3502x; 1.3502x over previous
//
#include <hip/hip_runtime.h>
#include <math.h>

// Problem constants (match reference)
constexpr int NB   = 8;            // batch
constexpr int ND   = 8;            // embedding dim
constexpr int NH   = 512;
constexpr int NW   = 1024;
constexpr int NP   = NH * NW;      // pixels per image = 524288
constexpr int NG   = NP / 4;       // float4 groups per image = 131072
constexpr int BPB  = 256;          // blocks per batch image (2048 total = 8/CU)
constexpr int GPB  = NG / BPB;     // float4 groups per block = 512
constexpr int NK   = 5;            // instance labels 1..NK
constexpr int NVAL = NK * ND + NK; // 45 reduced values in pass 1

constexpr float DELTA_V     = 0.5f;
constexpr float TWO_DELTA_D = 6.0f;   // 2 * DELTA_D
constexpr float GAMMA       = 0.001f;

__device__ __forceinline__ float wave_sum(float v) {
#pragma unroll
    for (int off = 32; off > 0; off >>= 1) v += __shfl_down(v, off, 64);
    return v;
}

// ---------------- Pass 1: per-(b,k) embedding sums + counts ----------------
// All hot-loop state in NAMED registers: no arrays, no address-taking -> no scratch.
__global__ __launch_bounds__(256) void pass1_kernel(const float* __restrict__ emb,
                                                    const int* __restrict__ mask,
                                                    float* __restrict__ sums,   // [NB][NK][ND]
                                                    float* __restrict__ cnts) { // [NB][NK]
    const int b   = blockIdx.x / BPB;
    const int blk = blockIdx.x % BPB;
    const long base = (long)blk * GPB;

    const float4* __restrict__ emb4 = (const float4*)emb + (long)b * ND * NG;
    const int4*   __restrict__ m4p  = (const int4*)mask + (long)b * NG;

    float4 zero4 = make_float4(0.f, 0.f, 0.f, 0.f);
    float4 a0l = zero4, a0h = zero4, a1l = zero4, a1h = zero4;
    float4 a2l = zero4, a2h = zero4, a3l = zero4, a3h = zero4;
    float4 a4l = zero4, a4h = zero4;
    float  n0 = 0.f, n1 = 0.f, n2 = 0.f, n3 = 0.f, n4 = 0.f;

    for (int it = threadIdx.x; it < GPB; it += 256) {
        const long g = base + it;
        const int4  m  = m4p[g];
        const float4 e0 = emb4[g];
        const float4 e1 = emb4[g + (long)NG];
        const float4 e2 = emb4[g + 2L * NG];
        const float4 e3 = emb4[g + 3L * NG];
        const float4 e4 = emb4[g + 4L * NG];
        const float4 e5 = emb4[g + 5L * NG];
        const float4 e6 = emb4[g + 6L * NG];
        const float4 e7 = emb4[g + 7L * NG];

#define KUPD1(KK, AL, AH, CN) { const float is = (lab == (KK)) ? 1.f : 0.f; CN += is; \
        AL.x = fmaf(is, f0, AL.x); AL.y = fmaf(is, f1, AL.y); \
        AL.z = fmaf(is, f2, AL.z); AL.w = fmaf(is, f3, AL.w); \
        AH.x = fmaf(is, f4, AH.x); AH.y = fmaf(is, f5, AH.y); \
        AH.z = fmaf(is, f6, AH.z); AH.w = fmaf(is, f7, AH.w); }

#define PIX1(LAB, CM) { const int lab = (LAB); \
        const float f0 = e0.CM, f1 = e1.CM, f2 = e2.CM, f3 = e3.CM; \
        const float f4 = e4.CM, f5 = e5.CM, f6 = e6.CM, f7 = e7.CM; \
        KUPD1(1, a0l, a0h, n0) KUPD1(2, a1l, a1h, n1) KUPD1(3, a2l, a2h, n2) \
        KUPD1(4, a3l, a3h, n3) KUPD1(5, a4l, a4h, n4) }

        PIX1(m.x, x) PIX1(m.y, y) PIX1(m.z, z) PIX1(m.w, w)
#undef PIX1
#undef KUPD1
    }

    // block reduction: wave shuffle -> LDS partials -> one atomic per value
    __shared__ float part[4][NVAL];
    const int lane = threadIdx.x & 63;
    const int wave = threadIdx.x >> 6;
#define RED1(V, IDX) { const float r = wave_sum(V); if (lane == 0) part[wave][IDX] = r; }
#define REDK1(AL, AH, CN, K) \
    RED1(AL.x, (K)*8 + 0) RED1(AL.y, (K)*8 + 1) RED1(AL.z, (K)*8 + 2) RED1(AL.w, (K)*8 + 3) \
    RED1(AH.x, (K)*8 + 4) RED1(AH.y, (K)*8 + 5) RED1(AH.z, (K)*8 + 6) RED1(AH.w, (K)*8 + 7) \
    RED1(CN, 40 + (K))
    REDK1(a0l, a0h, n0, 0) REDK1(a1l, a1h, n1, 1) REDK1(a2l, a2h, n2, 2)
    REDK1(a3l, a3h, n3, 3) REDK1(a4l, a4h, n4, 4)
#undef REDK1
#undef RED1
    __syncthreads();
    if (threadIdx.x < NVAL) {
        const float s = part[0][threadIdx.x] + part[1][threadIdx.x] +
                        part[2][threadIdx.x] + part[3][threadIdx.x];
        if (threadIdx.x < NK * ND)
            atomicAdd(&sums[b * NK * ND + threadIdx.x], s);
        else
            atomicAdd(&cnts[b * NK + (threadIdx.x - NK * ND)], s);
    }
}

// ---------------- Pass 2: per-(b,k) variance hinge sums ----------------
__global__ __launch_bounds__(256) void pass2_kernel(const float* __restrict__ emb,
                                                    const int* __restrict__ mask,
                                                    const float* __restrict__ sums,
                                                    const float* __restrict__ cnts,
                                                    float* __restrict__ vsums) { // [NB][NK]
    const int b   = blockIdx.x / BPB;
    const int blk = blockIdx.x % BPB;
    const long base = (long)blk * GPB;

    // centers in named registers (uniform across block -> scalarized)
    const float* sp = sums + b * NK * ND;
    const float inv0 = 1.f / fmaxf(cnts[b * NK + 0], 1.f);
    const float inv1 = 1.f / fmaxf(cnts[b * NK + 1], 1.f);
    const float inv2 = 1.f / fmaxf(cnts[b * NK + 2], 1.f);
    const float inv3 = 1.f / fmaxf(cnts[b * NK + 3], 1.f);
    const float inv4 = 1.f / fmaxf(cnts[b * NK + 4], 1.f);
    const float4 c0l = make_float4(sp[0]*inv0,  sp[1]*inv0,  sp[2]*inv0,  sp[3]*inv0);
    const float4 c0h = make_float4(sp[4]*inv0,  sp[5]*inv0,  sp[6]*inv0,  sp[7]*inv0);
    const float4 c1l = make_float4(sp[8]*inv1,  sp[9]*inv1,  sp[10]*inv1, sp[11]*inv1);
    const float4 c1h = make_float4(sp[12]*inv1, sp[13]*inv1, sp[14]*inv1, sp[15]*inv1);
    const float4 c2l = make_float4(sp[16]*inv2, sp[17]*inv2, sp[18]*inv2, sp[19]*inv2);
    const float4 c2h = make_float4(sp[20]*inv2, sp[21]*inv2, sp[22]*inv2, sp[23]*inv2);
    const float4 c3l = make_float4(sp[24]*inv3, sp[25]*inv3, sp[26]*inv3, sp[27]*inv3);
    const float4 c3h = make_float4(sp[28]*inv3, sp[29]*inv3, sp[30]*inv3, sp[31]*inv3);
    const float4 c4l = make_float4(sp[32]*inv4, sp[33]*inv4, sp[34]*inv4, sp[35]*inv4);
    const float4 c4h = make_float4(sp[36]*inv4, sp[37]*inv4, sp[38]*inv4, sp[39]*inv4);

    const float4* __restrict__ emb4 = (const float4*)emb + (long)b * ND * NG;
    const int4*   __restrict__ m4p  = (const int4*)mask + (long)b * NG;

    float v0 = 0.f, v1 = 0.f, v2 = 0.f, v3 = 0.f, v4 = 0.f;

    for (int it = threadIdx.x; it < GPB; it += 256) {
        const long g = base + it;
        const int4  m  = m4p[g];
        const float4 e0 = emb4[g];
        const float4 e1 = emb4[g + (long)NG];
        const float4 e2 = emb4[g + 2L * NG];
        const float4 e3 = emb4[g + 3L * NG];
        const float4 e4 = emb4[g + 4L * NG];
        const float4 e5 = emb4[g + 5L * NG];
        const float4 e6 = emb4[g + 6L * NG];
        const float4 e7 = emb4[g + 7L * NG];

#define SEL2(F) ((lab == 1) ? c0##F : (lab == 2) ? c1##F : (lab == 3) ? c2##F : \
                 (lab == 4) ? c3##F : c4##F)
#define PIX2(LAB, CM) { const int lab = (LAB); \
        const float f0 = e0.CM, f1 = e1.CM, f2 = e2.CM, f3 = e3.CM; \
        const float f4 = e4.CM, f5 = e5.CM, f6 = e6.CM, f7 = e7.CM; \
        float dd = f0 - SEL2(l.x); float dsq = dd * dd; \
        dd = f1 - SEL2(l.y); dsq = fmaf(dd, dd, dsq); \
        dd = f2 - SEL2(l.z); dsq = fmaf(dd, dd, dsq); \
        dd = f3 - SEL2(l.w); dsq = fmaf(dd, dd, dsq); \
        dd = f4 - SEL2(h.x); dsq = fmaf(dd, dd, dsq); \
        dd = f5 - SEL2(h.y); dsq = fmaf(dd, dd, dsq); \
        dd = f6 - SEL2(h.z); dsq = fmaf(dd, dd, dsq); \
        dd = f7 - SEL2(h.w); dsq = fmaf(dd, dd, dsq); \
        const float dist = sqrtf(dsq); \
        const float hv = fmaxf(dist - DELTA_V, 0.f); \
        const float val = hv * hv; \
        v0 += (lab == 1) ? val : 0.f; v1 += (lab == 2) ? val : 0.f; \
        v2 += (lab == 3) ? val : 0.f; v3 += (lab == 4) ? val : 0.f; \
        v4 += (lab == 5) ? val : 0.f; }

        PIX2(m.x, x) PIX2(m.y, y) PIX2(m.z, z) PIX2(m.w, w)
#undef PIX2
#undef SEL2
    }

    __shared__ float part[4][NK];
    const int lane = threadIdx.x & 63;
    const int wave = threadIdx.x >> 6;
#define RED2(V, IDX) { const float r = wave_sum(V); if (lane == 0) part[wave][IDX] = r; }
    RED2(v0, 0) RED2(v1, 1) RED2(v2, 2) RED2(v3, 3) RED2(v4, 4)
#undef RED2
    __syncthreads();
    if (threadIdx.x < NK) {
        const float s = part[0][threadIdx.x] + part[1][threadIdx.x] +
                        part[2][threadIdx.x] + part[3][threadIdx.x];
        atomicAdd(&vsums[b * NK + threadIdx.x], s);
    }
}

// ---------------- Final: tiny O(B*K^2) epilogue, 8-way parallel over batch ----------------
__global__ void final_kernel(const float* __restrict__ sums,
                             const float* __restrict__ cnts,
                             const float* __restrict__ vsums,
                             float* __restrict__ out) {
    __shared__ float bl[4][NB];
    const int bb = threadIdx.x;
    if (bb < NB) {
        float cc[NK];
        bool  pres[NK];
        float c[NK][ND];
        float N = 0.f;
#pragma unroll
        for (int k = 0; k < NK; ++k) {
            cc[k]   = cnts[bb * NK + k];
            pres[k] = cc[k] > 0.f;
            if (pres[k]) N += 1.f;
            const float inv = 1.f / fmaxf(cc[k], 1.f);
#pragma unroll
            for (int d = 0; d < ND; ++d)
                c[k][d] = sums[bb * NK * ND + k * ND + d] * inv;
        }
        // variance loss
        float lv = 0.f;
#pragma unroll
        for (int k = 0; k < NK; ++k)
            if (pres[k]) lv += vsums[bb * NK + k] / fmaxf(cc[k], 1.f);
        lv /= fmaxf(N, 1.f);
        // distance loss (pairwise i<j)
        float ld = 0.f;
#pragma unroll
        for (int i = 0; i < NK; ++i)
#pragma unroll
            for (int j = i + 1; j < NK; ++j)
                if (pres[i] && pres[j]) {
                    float dsq = 0.f;
#pragma unroll
                    for (int d = 0; d < ND; ++d) {
                        const float df = c[i][d] - c[j][d];
                        dsq = fmaf(df, df, dsq);
                    }
                    const float t = fmaxf(TWO_DELTA_D - sqrtf(dsq), 0.f);
                    ld += t * t;
                }
        const float npairs = N * (N - 1.f) * 0.5f;
        ld /= (N > 1.f) ? npairs : 1.f;
        // regularization
        float lr = 0.f;
#pragma unroll
        for (int k = 0; k < NK; ++k)
            if (pres[k]) {
                float sq = 0.f;
#pragma unroll
                for (int d = 0; d < ND; ++d) sq = fmaf(c[k][d], c[k][d], sq);
                lr += sqrtf(sq);
            }
        lr /= fmaxf(N, 1.f);

        const float has = (N > 0.f) ? 1.f : 0.f;
        bl[0][bb] = lv * has;
        bl[1][bb] = ld * has;
        bl[2][bb] = lr * has;
        bl[3][bb] = has;
    }
    __syncthreads();
    if (threadIdx.x == 0) {
        float tv = 0.f, td = 0.f, tr = 0.f, hs = 0.f;
        for (int i = 0; i < NB; ++i) {
            tv += bl[0][i]; td += bl[1][i]; tr += bl[2][i]; hs += bl[3][i];
        }
        const float denom = fmaxf(hs, 1.f);
        tv /= denom; td /= denom; tr /= denom;
        out[0] = tv + td + GAMMA * tr;
        out[1] = tv;
        out[2] = td;
        out[3] = tr;
    }
}

extern "C" void kernel_launch(void* const* d_in, const int* in_sizes, int n_in,
                              void* d_out, int out_size, void* d_ws, size_t ws_size,
                              hipStream_t stream) {
    const float* emb  = (const float*)d_in[0];
    const int*   mask = (const int*)d_in[1];
    float* out = (float*)d_out;

    float* sums  = (float*)d_ws;                 // NB*NK*ND = 320
    float* cnts  = sums + NB * NK * ND;          // NB*NK    = 40
    float* vsums = cnts + NB * NK;               // NB*NK    = 40

    hipMemsetAsync(d_ws, 0, (size_t)(NB * NK * ND + 2 * NB * NK) * sizeof(float), stream);

    dim3 grid(NB * BPB), block(256);
    pass1_kernel<<<grid, block, 0, stream>>>(emb, mask, sums, cnts);
    pass2_kernel<<<grid, block, 0, stream>>>(emb, mask, sums, cnts, vsums);
    final_kernel<<<1, 64, 0, stream>>>(sums, cnts, vsums, out);
}